// Round 8
// baseline (275.922 us; speedup 1.0000x reference)
//
#include <hip/hip_runtime.h>
#include <stdint.h>

// ---------------------------------------------------------------------------
// GCN block: 3 x [ h = leaky_relu(in @ W);  out = adj@h + h ]   (I folded OUT)
// B=64, N=4096, D=16.  GEMM M=4096 x C=1024 x K=4096 in FP8 e4m3 MFMA.
// Round 8: r7 falsified barrier-count theory; r6 sits at ~71% of the fp8
// MFMA ceiling AND ~90% of its LDS-byte budget.  Raise intensity: wave-tile
// 64x64 -> 128x64 (acc 8x4 16x16 tiles = 128 VGPRs), block 256x128, BK=128.
// Per-MAC LDS bytes 46 -> 34; per-CU 3 MB -> 2.25 MB.  ks=4 keeps grid 512
// (2 blocks/CU).  Same verified swizzle / b128 frag reads / DMA pattern.
// ws: adj8 16MB | hb8 4MB | hnc 8MB | p0..p3 32MB = 60MB
// ---------------------------------------------------------------------------

typedef float  f32x4  __attribute__((ext_vector_type(4)));
typedef unsigned short ushort8 __attribute__((ext_vector_type(8)));
typedef long   i64x2  __attribute__((ext_vector_type(2)));

typedef __attribute__((address_space(1))) void* as1p;
typedef __attribute__((address_space(3))) void* as3p;
#define GLOAD_LDS16(G, L) \
  __builtin_amdgcn_global_load_lds((as1p)(G), (as3p)(L), 16, 0, 0)

#define P_ELEMS 4194304       // elems per partial buffer (4096*1024)
#define ADJ_SCALE 4096.0f
#define ADJ_DESCALE (1.0f / 4096.0f)

__device__ __forceinline__ unsigned short f2bf(float f) {
  unsigned u = __float_as_uint(f);
  u += 0x7fffu + ((u >> 16) & 1u);  // RNE
  return (unsigned short)(u >> 16);
}
__device__ __forceinline__ float bf2f(unsigned short u) {
  return __uint_as_float(((unsigned)u) << 16);
}
// pack 4 fp32 -> 4 fp8 e4m3 bytes (RNE, saturating)
__device__ __forceinline__ int pk4_fp8(float a, float b, float c, float d) {
  int v = __builtin_amdgcn_cvt_pk_fp8_f32(a, b, 0, false);   // bytes 0,1
  v = __builtin_amdgcn_cvt_pk_fp8_f32(c, d, v, true);        // bytes 2,3
  return v;
}

// ---------------------------------------------------------------------------
// adj8 = e4m3(adj * 4096), 4096x4096.  1 thread = 16 contiguous elements.
// ---------------------------------------------------------------------------
__global__ void make_adj8(const float* __restrict__ adj,
                          unsigned char* __restrict__ a8) {
  size_t base = ((size_t)blockIdx.x * 256 + threadIdx.x) * 16;
  const float4* src = (const float4*)(adj + base);
  float4 q0 = src[0], q1 = src[1], q2 = src[2], q3 = src[3];
  int4 o;
  o.x = pk4_fp8(q0.x * ADJ_SCALE, q0.y * ADJ_SCALE, q0.z * ADJ_SCALE, q0.w * ADJ_SCALE);
  o.y = pk4_fp8(q1.x * ADJ_SCALE, q1.y * ADJ_SCALE, q1.z * ADJ_SCALE, q1.w * ADJ_SCALE);
  o.z = pk4_fp8(q2.x * ADJ_SCALE, q2.y * ADJ_SCALE, q2.z * ADJ_SCALE, q2.w * ADJ_SCALE);
  o.w = pk4_fp8(q3.x * ADJ_SCALE, q3.y * ADJ_SCALE, q3.z * ADJ_SCALE, q3.w * ADJ_SCALE);
  *(int4*)(a8 + base) = o;
}

// ---------------------------------------------------------------------------
// linear layer, 64n x 64c tile per block, grid (64,16).
// mode 0: u = x (fp32 (b,n,d))                 [layer 0]
// mode 1: u = p0+p1+p2+p3 + h_nc (bf16)        [layers 1,2]
// h = leaky_relu(u @ W); writes hb8 fp8 [c][n] (LDS transpose) and
// h_nc bf16 [n][c] (identity term for consumers).
// ---------------------------------------------------------------------------
__global__ void linear_fuse(const float* __restrict__ x,
                            const unsigned short* __restrict__ pp,
                            const unsigned short* __restrict__ hnc_in,
                            const float* __restrict__ W,
                            unsigned char* __restrict__ hb8,
                            unsigned short* __restrict__ hnc_out,
                            int mode) {
  __shared__ float xs[64 * 65];
  __shared__ unsigned short ht[64 * 72];
  int n0 = blockIdx.x * 64, c0 = blockIdx.y * 64;

  if (mode == 0) {
    for (int i = threadIdx.x; i < 1024; i += 256) {
      int bs = i >> 8, rem = i & 255, nr = rem >> 2, d4 = rem & 3;
      float4 v = *(const float4*)(
          x + ((size_t)(c0 / 16 + bs) * 4096 + n0 + nr) * 16 + d4 * 4);
      float* dst = xs + nr * 65 + bs * 16 + d4 * 4;
      dst[0] = v.x; dst[1] = v.y; dst[2] = v.z; dst[3] = v.w;
    }
  } else {
    for (int i = threadIdx.x; i < 512; i += 256) {
      int row = i >> 3, ch = i & 7;
      size_t g = (size_t)(n0 + row) * 1024 + c0 + ch * 8;
      ushort8 a0 = *(const ushort8*)(pp + g);
      ushort8 a1 = *(const ushort8*)(pp + (size_t)P_ELEMS + g);
      ushort8 a2 = *(const ushort8*)(pp + (size_t)2 * P_ELEMS + g);
      ushort8 a3 = *(const ushort8*)(pp + (size_t)3 * P_ELEMS + g);
      ushort8 c = *(const ushort8*)(hnc_in + g);
      float* dst = xs + row * 65 + ch * 8;
#pragma unroll
      for (int j = 0; j < 8; ++j)
        dst[j] = (bf2f(a0[j]) + bf2f(a1[j])) + (bf2f(a2[j]) + bf2f(a3[j])) + bf2f(c[j]);
    }
  }
  __syncthreads();

  int n_l = threadIdx.x & 63, b_l = threadIdx.x >> 6;   // b_l 0..3
  float xv[16];
#pragma unroll
  for (int d = 0; d < 16; ++d) xv[d] = xs[n_l * 65 + b_l * 16 + d];
  float accv[16];
#pragma unroll
  for (int e = 0; e < 16; ++e) accv[e] = 0.f;
#pragma unroll
  for (int d = 0; d < 16; ++d)
#pragma unroll
    for (int e = 0; e < 16; ++e) accv[e] += xv[d] * W[d * 16 + e];

  ushort8 h0, h1;
#pragma unroll
  for (int e = 0; e < 16; ++e) {
    float a = accv[e] > 0.f ? accv[e] : 0.2f * accv[e];
    unsigned short hv = f2bf(a);
    ht[(b_l * 16 + e) * 72 + n_l] = hv;
    if (e < 8) h0[e] = hv; else h1[e - 8] = hv;
  }
  unsigned short* ho = hnc_out + (size_t)(n0 + n_l) * 1024 + c0 + b_l * 16;
  *(ushort8*)(ho)     = h0;
  *(ushort8*)(ho + 8) = h1;
  __syncthreads();

  // fp8 transposed store: 64 c-rows x 8 chunks of 8 bf16 -> 8 fp8 bytes
  for (int i = threadIdx.x; i < 512; i += 256) {
    int row = i >> 3, ch = i & 7;
    const unsigned short* s = ht + row * 72 + ch * 8;
    int2 v;
    v.x = pk4_fp8(bf2f(s[0]), bf2f(s[1]), bf2f(s[2]), bf2f(s[3]));
    v.y = pk4_fp8(bf2f(s[4]), bf2f(s[5]), bf2f(s[6]), bf2f(s[7]));
    *(int2*)(hb8 + (size_t)(c0 + row) * 4096 + n0 + ch * 8) = v;
  }
}

// ---------------------------------------------------------------------------
// final: out fp32 (b,n,d) = p0+p1+p2+p3 + h_nc   (all stored [n][c] bf16)
// ---------------------------------------------------------------------------
__global__ void add_out(const unsigned short* __restrict__ pp,
                        const unsigned short* __restrict__ hnc,
                        float* __restrict__ out) {
  int gid = blockIdx.x * 256 + threadIdx.x;      // 0..524287
  int n = gid >> 7, c8 = (gid & 127) * 8;
  size_t g = (size_t)n * 1024 + c8;
  ushort8 a0 = *(const ushort8*)(pp + g);
  ushort8 a1 = *(const ushort8*)(pp + (size_t)P_ELEMS + g);
  ushort8 a2 = *(const ushort8*)(pp + (size_t)2 * P_ELEMS + g);
  ushort8 a3 = *(const ushort8*)(pp + (size_t)3 * P_ELEMS + g);
  ushort8 h = *(const ushort8*)(hnc + g);
  float v[8];
#pragma unroll
  for (int j = 0; j < 8; ++j)
    v[j] = (bf2f(a0[j]) + bf2f(a1[j])) + (bf2f(a2[j]) + bf2f(a3[j])) + bf2f(h[j]);
  int bb = c8 >> 4, d0 = c8 & 15;                // d0 = 0 or 8
  float* o = out + (size_t)bb * 65536 + n * 16 + d0;
  *(float4*)(o)     = float4{v[0], v[1], v[2], v[3]};
  *(float4*)(o + 4) = float4{v[4], v[5], v[6], v[7]};
}

// ---------------------------------------------------------------------------
// p[ks][n][c] = (adj8[n0..][k] * hb8[c0..][k]) / 4096  (one K-quarter/block)
// fp8 e4m3 MFMA 16x16x32, tile 256x128, BK=128, 8 iters.
// 4 waves, wave grid 2m x 2n, wave tile 128x64 (8t x 4u of 16x16) ->
// 128 acc VGPRs, per-MAC LDS bytes 0.73x of r6.
// grid 512 = 16mt x 8ct x 4ks, xcd = mt&7 (A slice pinned per XCD).
// Swizzle (verified 0-conflict): phys 16B chunk = logical ^ (row&7).
// ---------------------------------------------------------------------------
__global__ __launch_bounds__(256, 2)
void gemm_f8(const unsigned char* __restrict__ A,
             const unsigned char* __restrict__ B8,
             unsigned short* __restrict__ pp) {
  const int K = 4096;
  __shared__ unsigned char a_s[256 * 128];   // 32 KB
  __shared__ unsigned char b_s[128 * 128];   // 16 KB

  int tid = threadIdx.x, wave = tid >> 6, lane = tid & 63;

  int lin = blockIdx.x;
  int xcd = lin & 7, g = lin >> 3;           // g 0..63
  int mth = g & 1, ct = (g >> 1) & 7, ks = g >> 4;   // 2 x 8 x 4
  int mt = mth * 8 + xcd;                    // 0..15
  int n0 = mt * 256, c0 = ct * 128;
  int kbase = ks * 1024;

  // staging: 8-row DMA units; lane: l8 = row-in-unit, lc = phys chunk
  int l8 = lane >> 3, lc = lane & 7;
  int swc = lc ^ l8;                 // logical chunk fetched into phys lc
  const unsigned char* gA[8];        // A: 256 rows = 8 insts/wave
  const unsigned char* gB[4];        // B: 128 rows = 4 insts/wave
#pragma unroll
  for (int j = 0; j < 8; ++j) {
    int r = wave * 64 + j * 8 + l8;
    gA[j] = A + (size_t)(n0 + r) * K + kbase + swc * 16;
  }
#pragma unroll
  for (int j = 0; j < 4; ++j) {
    int r = wave * 32 + j * 8 + l8;
    gB[j] = B8 + (size_t)(c0 + r) * K + kbase + swc * 16;
  }

  int i16 = lane & 15, q = lane >> 4;
  int wm = wave >> 1, wn = wave & 1;
  int sw7 = i16 & 7;

  f32x4 acc[8][4] = {};              // 128 VGPRs

  for (int it = 0; it < 8; ++it) {
    int k0 = it * 128;
    __syncthreads();                 // prev reads done before overwrite
#pragma unroll
    for (int j = 0; j < 8; ++j)
      GLOAD_LDS16(gA[j] + k0, a_s + (wave * 64 + j * 8) * 128);
#pragma unroll
    for (int j = 0; j < 4; ++j)
      GLOAD_LDS16(gB[j] + k0, b_s + (wave * 32 + j * 8) * 128);
    __syncthreads();                 // drains staging -> visible
#pragma unroll
    for (int s = 0; s < 2; ++s) {
      int pc = ((s * 4 + q) ^ sw7) * 16;
      i64x2 bv[4];
#pragma unroll
      for (int u = 0; u < 4; ++u)
        bv[u] = *(const i64x2*)(b_s + (wn * 64 + u * 16 + i16) * 128 + pc);
#pragma unroll
      for (int t = 0; t < 8; ++t) {
        i64x2 av = *(const i64x2*)(a_s + (wm * 128 + t * 16 + i16) * 128 + pc);
#pragma unroll
        for (int u = 0; u < 4; ++u) {
          acc[t][u] = __builtin_amdgcn_mfma_f32_16x16x32_fp8_fp8(av.x, bv[u].x, acc[t][u], 0, 0, 0);
          acc[t][u] = __builtin_amdgcn_mfma_f32_16x16x32_fp8_fp8(av.y, bv[u].y, acc[t][u], 0, 0, 0);
        }
      }
    }
  }

  // epilogue: descale + bf16 store of this K-quarter's partial
  unsigned short* dst = pp + (size_t)ks * P_ELEMS;
#pragma unroll
  for (int t = 0; t < 8; ++t)
#pragma unroll
    for (int u = 0; u < 4; ++u)
#pragma unroll
      for (int i = 0; i < 4; ++i) {
        int n_g = n0 + wm * 128 + t * 16 + q * 4 + i;
        int c_g = c0 + wn * 64 + u * 16 + i16;
        dst[(size_t)n_g * 1024 + c_g] = f2bf(acc[t][u][i] * ADJ_DESCALE);
      }
}

// ---------------------------------------------------------------------------
extern "C" void kernel_launch(void* const* d_in, const int* in_sizes, int n_in,
                              void* d_out, int out_size, void* d_ws, size_t ws_size,
                              hipStream_t stream) {
  const float* x   = (const float*)d_in[0];
  const float* adj = (const float*)d_in[1];
  // d_in[2] = Identity (handled as the +h_nc term)
  const float* W0  = (const float*)d_in[3];
  const float* W1  = (const float*)d_in[4];
  const float* W2  = (const float*)d_in[5];
  float* out = (float*)d_out;

  char* ws = (char*)d_ws;
  unsigned char*  adj8 = (unsigned char*)ws;                   // 16 MiB
  unsigned char*  hb8  = (unsigned char*)(ws + 16777216);      //  4 MiB
  unsigned short* hnc  = (unsigned short*)(ws + 20971520);     //  8 MiB
  unsigned short* pp   = (unsigned short*)(ws + 29360128);     // p0..p3 32 MiB

  make_adj8<<<4096, 256, 0, stream>>>(adj, adj8);

  // layer 0
  linear_fuse<<<dim3(64, 16), 256, 0, stream>>>(x, pp, hnc, W0, hb8, hnc, 0);
  gemm_f8<<<512, 256, 0, stream>>>(adj8, hb8, pp);
  // layer 1
  linear_fuse<<<dim3(64, 16), 256, 0, stream>>>(x, pp, hnc, W1, hb8, hnc, 1);
  gemm_f8<<<512, 256, 0, stream>>>(adj8, hb8, pp);
  // layer 2
  linear_fuse<<<dim3(64, 16), 256, 0, stream>>>(x, pp, hnc, W2, hb8, hnc, 1);
  gemm_f8<<<512, 256, 0, stream>>>(adj8, hb8, pp);
  add_out<<<2048, 256, 0, stream>>>(pp, hnc, out);
}